// Round 2
// baseline (1033.765 us; speedup 1.0000x reference)
//
#include <hip/hip_runtime.h>

typedef float f32x4 __attribute__((ext_vector_type(4)));
typedef _Float16 f16x8 __attribute__((ext_vector_type(8)));

constexpr int kB = 128;     // batch
constexpr int kT = 512;     // time
constexpr int kD = 256;     // emb dim
constexpr int kG = 512;     // 4*H gates per direction
constexpr int kH = 128;     // hidden
constexpr int kK = 9;       // CRF states
constexpr int kSTART = 7;
constexpr int kSTOP = 8;

// ---------------------------------------------------------------------------
// Kernel 1: embedding gather + input projection (f16 MFMA GEMM)
// C[r, n] = emb[sentence[r]] . W[n] + bias[n],  r=(b,t), n in [0,1024)
// n<512 -> forward gates, n>=512 -> backward gates. Output f16 to gi.
// ---------------------------------------------------------------------------
__global__ __launch_bounds__(256) void proj_kernel(
    const int* __restrict__ sentence, const int* __restrict__ lengths,
    const float* __restrict__ emb,
    const float* __restrict__ Wih_f, const float* __restrict__ b_f,
    const float* __restrict__ Wih_b, const float* __restrict__ b_b,
    _Float16* __restrict__ gi)
{
    __shared__ __align__(16) _Float16 smemA[128 * 256]; // rows=t, 512B/row
    __shared__ __align__(16) _Float16 smemW[128 * 256]; // rows=n, 512B/row

    const int bx = blockIdx.x;            // 512 row tiles (4 per batch)
    const int by = blockIdx.y;            // 8 col tiles
    const int b  = bx >> 2;
    const int t0 = (bx & 3) << 7;
    const int len = lengths[b];
    if (t0 >= len) return;                // whole tile beyond length
    const int tid = threadIdx.x;
    const int dir = by >> 2;

    // ---- stage A (gathered embedding rows, f32 -> f16, swizzled) ----
    {
        const int row = tid >> 1;
        const int kb  = (tid & 1) << 7;   // 0 or 128
        const int vocab = sentence[b * kT + t0 + row];
        const float* src = emb + (size_t)vocab * kD + kb;
        const unsigned rowbyte = row * 512;
        const unsigned sw = (row & 7) << 4;
        #pragma unroll
        for (int c = 0; c < 16; ++c) {
            float4 x0 = *(const float4*)(src + c * 8);
            float4 x1 = *(const float4*)(src + c * 8 + 4);
            f16x8 pk;
            pk[0] = (_Float16)x0.x; pk[1] = (_Float16)x0.y;
            pk[2] = (_Float16)x0.z; pk[3] = (_Float16)x0.w;
            pk[4] = (_Float16)x1.x; pk[5] = (_Float16)x1.y;
            pk[6] = (_Float16)x1.z; pk[7] = (_Float16)x1.w;
            unsigned byteoff = rowbyte + ((unsigned)((kb + c * 8) * 2) ^ sw);
            *(f16x8*)((char*)smemA + byteoff) = pk;
        }
    }
    // ---- stage W (weight rows for this col tile) ----
    {
        const int row = tid >> 1;
        const int kb  = (tid & 1) << 7;
        const int n_g = by * 128 + row;
        const int gate = n_g & (kG - 1);
        const float* src = (dir == 0 ? Wih_f : Wih_b) + (size_t)gate * kD + kb;
        const unsigned rowbyte = row * 512;
        const unsigned sw = (row & 7) << 4;
        #pragma unroll
        for (int c = 0; c < 16; ++c) {
            float4 x0 = *(const float4*)(src + c * 8);
            float4 x1 = *(const float4*)(src + c * 8 + 4);
            f16x8 pk;
            pk[0] = (_Float16)x0.x; pk[1] = (_Float16)x0.y;
            pk[2] = (_Float16)x0.z; pk[3] = (_Float16)x0.w;
            pk[4] = (_Float16)x1.x; pk[5] = (_Float16)x1.y;
            pk[6] = (_Float16)x1.z; pk[7] = (_Float16)x1.w;
            unsigned byteoff = rowbyte + ((unsigned)((kb + c * 8) * 2) ^ sw);
            *(f16x8*)((char*)smemW + byteoff) = pk;
        }
    }
    __syncthreads();

    // ---- compute: 4 waves in 2x2 grid, each 64x64 ----
    const int w    = tid >> 6;
    const int lane = tid & 63;
    const int wr = w >> 1, wc = w & 1;
    const int l15 = lane & 15, l4 = lane >> 4;

    f32x4 zero = {0.f, 0.f, 0.f, 0.f};
    f32x4 acc[4][4];
    #pragma unroll
    for (int mf = 0; mf < 4; ++mf)
        #pragma unroll
        for (int nf = 0; nf < 4; ++nf) acc[mf][nf] = zero;

    #pragma unroll
    for (int kk = 0; kk < 8; ++kk) {
        f16x8 afr[4], bfr[4];
        #pragma unroll
        for (int mf = 0; mf < 4; ++mf) {
            int row = wr * 64 + mf * 16 + l15;
            unsigned byteoff = row * 512 +
                ((unsigned)(kk * 64 + l4 * 16) ^ (unsigned)((row & 7) << 4));
            afr[mf] = *(const f16x8*)((const char*)smemA + byteoff);
        }
        #pragma unroll
        for (int nf = 0; nf < 4; ++nf) {
            int row = wc * 64 + nf * 16 + l15;
            unsigned byteoff = row * 512 +
                ((unsigned)(kk * 64 + l4 * 16) ^ (unsigned)((row & 7) << 4));
            bfr[nf] = *(const f16x8*)((const char*)smemW + byteoff);
        }
        #pragma unroll
        for (int mf = 0; mf < 4; ++mf)
            #pragma unroll
            for (int nf = 0; nf < 4; ++nf)
                acc[mf][nf] = __builtin_amdgcn_mfma_f32_16x16x32_f16(
                    afr[mf], bfr[nf], acc[mf][nf], 0, 0, 0);
    }

    // ---- epilogue: add bias, write f16 gi[dir][b][t][gate] ----
    const float* biasp = (dir == 0) ? b_f : b_b;
    #pragma unroll
    for (int nf = 0; nf < 4; ++nf) {
        int n_loc = wc * 64 + nf * 16 + l15;
        int n_g = by * 128 + n_loc;
        int gate = n_g & (kG - 1);
        float bias = biasp[gate];
        #pragma unroll
        for (int mf = 0; mf < 4; ++mf) {
            #pragma unroll
            for (int rg = 0; rg < 4; ++rg) {
                int m_loc = wr * 64 + mf * 16 + l4 * 4 + rg;
                int t = t0 + m_loc;
                float v = acc[mf][nf][rg] + bias;
                gi[(((size_t)dir * kB + b) * kT + t) * kG + gate] = (_Float16)v;
            }
        }
    }
}

// ---------------------------------------------------------------------------
// Kernel 2: LSTM recurrence, one workgroup per (batch, direction) chain.
// 512 threads: thread j owns gate row j of Whh (in VGPRs). Fused feats proj.
// ---------------------------------------------------------------------------
__device__ inline float sigm(float x) { return 1.f / (1.f + __expf(-x)); }
__device__ inline float tanh_(float x) {
    float t = __expf(-2.f * fabsf(x));
    float r = (1.f - t) / (1.f + t);
    return x >= 0.f ? r : -r;
}

__global__ __launch_bounds__(512) void lstm_kernel(
    const _Float16* __restrict__ gi, const int* __restrict__ lengths,
    const float* __restrict__ Whh_f, const float* __restrict__ Whh_b,
    const float* __restrict__ Wt, const float* __restrict__ bt,
    float* __restrict__ feats_f, float* __restrict__ feats_b)
{
    const int bid = blockIdx.x;
    const int dir = bid >> 7;
    const int b   = bid & 127;
    const int len = lengths[b];
    const int tid = threadIdx.x;

    __shared__ __align__(16) float h_lds[kH];
    __shared__ float g_lds[kG];
    __shared__ float p_lds[72];
    __shared__ float wt_lds[kK * kH];

    const float* Whh = dir ? Whh_b : Whh_f;
    f32x4 w4[32];
    {
        const f32x4* wsrc = (const f32x4*)(Whh + (size_t)tid * kH);
        #pragma unroll
        for (int k = 0; k < 32; ++k) w4[k] = wsrc[k];
    }
    for (int idx = tid; idx < kK * kH; idx += 512)
        wt_lds[idx] = Wt[(idx >> 7) * 256 + dir * kH + (idx & 127)];
    if (tid < kH) h_lds[tid] = 0.f;
    float c = 0.f;

    const _Float16* gip = gi + ((size_t)(dir * kB + b)) * kT * kG;
    float* fout = (dir ? feats_b : feats_f) + (size_t)b * kT * kK;
    __syncthreads();

    int tfirst = dir ? (len - 1) : 0;
    float gival = (float)gip[(size_t)tfirst * kG + tid];

    for (int s = 0; s < len; ++s) {
        const int tcur = dir ? (len - 1 - s) : s;
        float cur = gival;
        if (s + 1 < len) {
            int tn = dir ? (len - 2 - s) : (s + 1);
            gival = (float)gip[(size_t)tn * kG + tid];   // prefetch next step
        }
        // gate GEMV: g[j] = gi + sum_k Whh[j,k] * h[k]
        float acc = 0.f;
        const f32x4* h4 = (const f32x4*)h_lds;
        #pragma unroll
        for (int k = 0; k < 32; ++k) {
            f32x4 hv = h4[k];
            acc += w4[k][0] * hv[0] + w4[k][1] * hv[1] +
                   w4[k][2] * hv[2] + w4[k][3] * hv[3];
        }
        g_lds[tid] = cur + acc;
        __syncthreads();                                  // B1
        if (tid < kH) {
            float gi_ = g_lds[tid], gf_ = g_lds[kH + tid];
            float gg_ = g_lds[2 * kH + tid], go_ = g_lds[3 * kH + tid];
            c = sigm(gf_) * c + sigm(gi_) * tanh_(gg_);
            float h = sigm(go_) * tanh_(c);
            h_lds[tid] = h;
        }
        __syncthreads();                                  // B2
        if (tid < 72) {                                   // feats partials
            int k = tid >> 3, seg = tid & 7;
            float p = 0.f;
            #pragma unroll
            for (int i = 0; i < 16; ++i)
                p += h_lds[seg * 16 + i] * wt_lds[k * kH + seg * 16 + i];
            p_lds[tid] = p;
        }
        __syncthreads();                                  // B3
        if (tid < kK) {
            float f = p_lds[tid * 8];
            #pragma unroll
            for (int q = 1; q < 8; ++q) f += p_lds[tid * 8 + q];
            if (!dir) f += bt[tid];
            fout[(size_t)tcur * kK + tid] = f;
        }
        // reducer re-syncs at next iteration's B1; p_lds/h_lds reuse is safe.
    }
}

// ---------------------------------------------------------------------------
// Kernel 3: CRF Viterbi via max-plus matrix reduction tree.
// M_t[k,j] = trans[k,j] + feat_t[k];  R = M_{len-1} (x) ... (x) M_0.
// Level 0 fused over 4 timesteps per output matrix (column-wise mat-vec
// chains, no shared intermediates). Then 7 tree levels 128->1 ping-ponging
// between two integer-offset regions of one LDS buffer.
// ---------------------------------------------------------------------------
__global__ __launch_bounds__(512) void viterbi_kernel(
    const int* __restrict__ lengths, const float* __restrict__ trans,
    const float* __restrict__ feats_f, const float* __restrict__ feats_b,
    float* __restrict__ out)
{
    constexpr float NEG = -1e30f;
    constexpr int RA = 0;            // region A: 128 matrices
    constexpr int RB = 128 * 81;     // region B: 64 matrices
    const int b = blockIdx.x;
    const int len = lengths[b];
    const int tid = threadIdx.x;

    __shared__ float tree[(128 + 64) * 81];
    __shared__ float fsum[kT * kK];
    __shared__ float trs[81];
    __shared__ float red[16];

    if (tid < 81) trs[tid] = trans[tid];
    for (int idx = tid; idx < len * kK; idx += 512)
        fsum[idx] = feats_f[(size_t)b * kT * kK + idx] +
                    feats_b[(size_t)b * kT * kK + idx];
    __syncthreads();

    // ---- fused level 0: each task = column j of R_s = M_{4s+3}..M_{4s} ----
    for (int task = tid; task < 128 * 9; task += 512) {
        int s = task / 9, j = task - s * 9;
        int tb = 4 * s;
        float u[9];
        #pragma unroll
        for (int m = 0; m < 9; ++m)
            u[m] = (tb < len) ? (trs[m * 9 + j] + fsum[tb * 9 + m])
                              : ((m == j) ? 0.f : NEG);
        #pragma unroll
        for (int q = 1; q < 4; ++q) {
            int t = tb + q;
            if (t < len) {
                float un[9];
                #pragma unroll
                for (int k = 0; k < 9; ++k) {
                    float v = trs[k * 9] + u[0];
                    #pragma unroll
                    for (int m = 1; m < 9; ++m)
                        v = fmaxf(v, trs[k * 9 + m] + u[m]);
                    un[k] = v + fsum[t * 9 + k];
                }
                #pragma unroll
                for (int k = 0; k < 9; ++k) u[k] = un[k];
            }
        }
        #pragma unroll
        for (int k = 0; k < 9; ++k)
            tree[RA + s * 81 + k * 9 + j] = u[k];
    }
    __syncthreads();

    // ---- tree levels: 64,32,...,1 matrices out ----
    int soff = RA, doff = RB;
    for (int np = 64; np >= 1; np >>= 1) {
        for (int idx = tid; idx < np * 81; idx += 512) {
            int s = idx / 81, o = idx - s * 81;
            int k = o / 9, j = o - k * 9;
            const float* A  = tree + soff + (2 * s + 1) * 81;
            const float* Bm = tree + soff + (2 * s) * 81;
            float v = A[k * 9] + Bm[j];
            #pragma unroll
            for (int m = 1; m < 9; ++m)
                v = fmaxf(v, A[k * 9 + m] + Bm[m * 9 + j]);
            tree[doff + s * 81 + o] = v;
        }
        int tmp = soff; soff = doff; doff = tmp;
        __syncthreads();
    }
    // final matrix at region soff (last written), index 0
    if (tid < kK) {
        int k = tid;
        float fv = tree[soff + k * 9 + kSTART];      // + fv0[START] = 0
        #pragma unroll
        for (int j = 0; j < 9; ++j)
            if (j != kSTART) fv = fmaxf(fv, tree[soff + k * 9 + j] - 10000.f);
        red[k] = fv + trs[kSTOP * 9 + k];
    }
    __syncthreads();
    if (tid == 0) {
        float m = red[0];
        #pragma unroll
        for (int k = 1; k < 9; ++k) m = fmaxf(m, red[k]);
        out[b] = m;
    }
}

// ---------------------------------------------------------------------------
extern "C" void kernel_launch(void* const* d_in, const int* in_sizes, int n_in,
                              void* d_out, int out_size, void* d_ws, size_t ws_size,
                              hipStream_t stream) {
    const int*   sentence = (const int*)d_in[0];
    const int*   lengths  = (const int*)d_in[1];
    const float* emb      = (const float*)d_in[2];
    const float* Wih_f    = (const float*)d_in[3];
    const float* Whh_f    = (const float*)d_in[4];
    const float* b_f      = (const float*)d_in[5];
    const float* Wih_b    = (const float*)d_in[6];
    const float* Whh_b    = (const float*)d_in[7];
    const float* b_b      = (const float*)d_in[8];
    const float* Wt       = (const float*)d_in[9];
    const float* bt       = (const float*)d_in[10];
    const float* trans    = (const float*)d_in[11];
    float* out = (float*)d_out;

    char* ws = (char*)d_ws;
    const size_t gi_bytes = (size_t)2 * kB * kT * kG * sizeof(_Float16); // 128 MiB
    const size_t ft_bytes = (size_t)kB * kT * kK * sizeof(float);        // 2.25 MiB
    _Float16* gi      = (_Float16*)ws;
    float*    feats_f = (float*)(ws + gi_bytes);
    float*    feats_b = (float*)(ws + gi_bytes + ft_bytes);

    dim3 g1((kB * kT) / 128, 1024 / 128);
    proj_kernel<<<g1, 256, 0, stream>>>(sentence, lengths, emb,
                                        Wih_f, b_f, Wih_b, b_b, gi);
    lstm_kernel<<<256, 512, 0, stream>>>(gi, lengths, Whh_f, Whh_b,
                                         Wt, bt, feats_f, feats_b);
    viterbi_kernel<<<128, 512, 0, stream>>>(lengths, trans, feats_f, feats_b, out);
}

// Round 3
// 893.397 us; speedup vs baseline: 1.1571x; 1.1571x over previous
//
#include <hip/hip_runtime.h>

typedef float f32x4 __attribute__((ext_vector_type(4)));
typedef _Float16 f16x8 __attribute__((ext_vector_type(8)));

constexpr int kB = 128;     // batch
constexpr int kT = 512;     // time
constexpr int kD = 256;     // emb dim
constexpr int kG = 512;     // 4*H gates per direction
constexpr int kH = 128;     // hidden
constexpr int kK = 9;       // CRF states
constexpr int kSTART = 7;
constexpr int kSTOP = 8;
constexpr int kNB = 16;     // chains per LSTM workgroup

// gi workspace layout (written by proj, read by lstm), f16:
//   [(dir*8+group)][t][w*64+lane][16]   16 = q*4 + reg  (q=gate block, reg=row%4)
// chain row r = (lane>>4)*4 + reg, unit u = w*16 + (lane&15), gate n = q*128+u.

// ---------------------------------------------------------------------------
// Kernel 1: embedding gather + input projection (f16 MFMA GEMM)
// ---------------------------------------------------------------------------
__global__ __launch_bounds__(256) void proj_kernel(
    const int* __restrict__ sentence, const int* __restrict__ lengths,
    const float* __restrict__ emb,
    const float* __restrict__ Wih_f, const float* __restrict__ b_f,
    const float* __restrict__ Wih_b, const float* __restrict__ b_b,
    _Float16* __restrict__ gi)
{
    __shared__ __align__(16) _Float16 smemA[128 * 256]; // rows=t, 512B/row
    __shared__ __align__(16) _Float16 smemW[128 * 256]; // rows=n, 512B/row

    const int bx = blockIdx.x;            // 512 row tiles (4 per batch)
    const int by = blockIdx.y;            // 8 col tiles
    const int b  = bx >> 2;
    const int t0 = (bx & 3) << 7;
    const int len = lengths[b];
    if (t0 >= len) return;                // whole tile beyond length
    const int tid = threadIdx.x;
    const int dir = by >> 2;

    // ---- stage A (gathered embedding rows, f32 -> f16, swizzled) ----
    {
        const int row = tid >> 1;
        const int kb  = (tid & 1) << 7;   // 0 or 128
        const int vocab = sentence[b * kT + t0 + row];
        const float* src = emb + (size_t)vocab * kD + kb;
        const unsigned rowbyte = row * 512;
        const unsigned sw = (row & 7) << 4;
        #pragma unroll
        for (int c = 0; c < 16; ++c) {
            float4 x0 = *(const float4*)(src + c * 8);
            float4 x1 = *(const float4*)(src + c * 8 + 4);
            f16x8 pk;
            pk[0] = (_Float16)x0.x; pk[1] = (_Float16)x0.y;
            pk[2] = (_Float16)x0.z; pk[3] = (_Float16)x0.w;
            pk[4] = (_Float16)x1.x; pk[5] = (_Float16)x1.y;
            pk[6] = (_Float16)x1.z; pk[7] = (_Float16)x1.w;
            unsigned byteoff = rowbyte + ((unsigned)((kb + c * 8) * 2) ^ sw);
            *(f16x8*)((char*)smemA + byteoff) = pk;
        }
    }
    // ---- stage W (weight rows for this col tile) ----
    {
        const int row = tid >> 1;
        const int kb  = (tid & 1) << 7;
        const int n_g = by * 128 + row;
        const int gate = n_g & (kG - 1);
        const float* src = (dir == 0 ? Wih_f : Wih_b) + (size_t)gate * kD + kb;
        const unsigned rowbyte = row * 512;
        const unsigned sw = (row & 7) << 4;
        #pragma unroll
        for (int c = 0; c < 16; ++c) {
            float4 x0 = *(const float4*)(src + c * 8);
            float4 x1 = *(const float4*)(src + c * 8 + 4);
            f16x8 pk;
            pk[0] = (_Float16)x0.x; pk[1] = (_Float16)x0.y;
            pk[2] = (_Float16)x0.z; pk[3] = (_Float16)x0.w;
            pk[4] = (_Float16)x1.x; pk[5] = (_Float16)x1.y;
            pk[6] = (_Float16)x1.z; pk[7] = (_Float16)x1.w;
            unsigned byteoff = rowbyte + ((unsigned)((kb + c * 8) * 2) ^ sw);
            *(f16x8*)((char*)smemW + byteoff) = pk;
        }
    }
    __syncthreads();

    // ---- compute: 4 waves in 2x2 grid, each 64x64 ----
    const int w    = tid >> 6;
    const int lane = tid & 63;
    const int wr = w >> 1, wc = w & 1;
    const int l15 = lane & 15, l4 = lane >> 4;

    f32x4 zero = {0.f, 0.f, 0.f, 0.f};
    f32x4 acc[4][4];
    #pragma unroll
    for (int mf = 0; mf < 4; ++mf)
        #pragma unroll
        for (int nf = 0; nf < 4; ++nf) acc[mf][nf] = zero;

    #pragma unroll
    for (int kk = 0; kk < 8; ++kk) {
        f16x8 afr[4], bfr[4];
        #pragma unroll
        for (int mf = 0; mf < 4; ++mf) {
            int row = wr * 64 + mf * 16 + l15;
            unsigned byteoff = row * 512 +
                ((unsigned)(kk * 64 + l4 * 16) ^ (unsigned)((row & 7) << 4));
            afr[mf] = *(const f16x8*)((const char*)smemA + byteoff);
        }
        #pragma unroll
        for (int nf = 0; nf < 4; ++nf) {
            int row = wc * 64 + nf * 16 + l15;
            unsigned byteoff = row * 512 +
                ((unsigned)(kk * 64 + l4 * 16) ^ (unsigned)((row & 7) << 4));
            bfr[nf] = *(const f16x8*)((const char*)smemW + byteoff);
        }
        #pragma unroll
        for (int mf = 0; mf < 4; ++mf)
            #pragma unroll
            for (int nf = 0; nf < 4; ++nf)
                acc[mf][nf] = __builtin_amdgcn_mfma_f32_16x16x32_f16(
                    afr[mf], bfr[nf], acc[mf][nf], 0, 0, 0);
    }

    // ---- epilogue: add bias, write f16 gi in lstm C-fragment layout ----
    const float* biasp = (dir == 0) ? b_f : b_b;
    const int q  = by & 3;        // gate block (n>>7)
    const int gg = b >> 4;        // chain group
    const int r  = b & 15;        // chain row within group
    _Float16* gbase = gi + ((size_t)(dir * 8 + gg) * kT) * 8192
                         + (size_t)(q * 4 + (r & 3));
    const int lanep = (r >> 2) * 16 + l15;
    #pragma unroll
    for (int nf = 0; nf < 4; ++nf) {
        int n_loc = wc * 64 + nf * 16 + l15;        // unit u (0..127)
        float bias = biasp[q * 128 + n_loc];
        _Float16* colp = gbase + (size_t)((n_loc >> 4) * 64 + lanep) * 16;
        #pragma unroll
        for (int mf = 0; mf < 4; ++mf) {
            #pragma unroll
            for (int rg = 0; rg < 4; ++rg) {
                int t = t0 + wr * 64 + mf * 16 + l4 * 4 + rg;
                colp[(size_t)t * 8192] = (_Float16)(acc[mf][nf][rg] + bias);
            }
        }
    }
}

// ---------------------------------------------------------------------------
// Kernel 2: persistent weight-stationary LSTM. 16 wgs x 512 thr.
// wg = (dir, group of 16 chains). Per step: 16x512x128 MFMA GEMM,
// in-register activation, h via double-buffered swizzled LDS, 1 barrier.
// ---------------------------------------------------------------------------
__device__ inline float sigm(float x) {
    return __builtin_amdgcn_rcpf(1.f + __expf(-x));
}
__device__ inline float tanh_(float x) {
    float t = __expf(-2.f * fabsf(x));
    float r = (1.f - t) * __builtin_amdgcn_rcpf(1.f + t);
    return x >= 0.f ? r : -r;
}

__global__ __launch_bounds__(512) void lstm_kernel(
    const _Float16* __restrict__ gi, const int* __restrict__ lengths,
    const float* __restrict__ Whh_f, const float* __restrict__ Whh_b,
    const float* __restrict__ Wt, const float* __restrict__ bt,
    float* __restrict__ feats_f, float* __restrict__ feats_b)
{
    const int bid = blockIdx.x;          // 0..15
    const int dir = bid >> 3;
    const int g   = bid & 7;
    const int tid = threadIdx.x;
    const int w   = tid >> 6;
    const int l   = tid & 63;
    const int l15 = l & 15, l4 = l >> 4;

    __shared__ __align__(16) _Float16 hbuf[2][kNB * kH];   // swizzled

    // ---- Whh B-fragments, resident in VGPRs for the whole kernel ----
    const float* Whh = dir ? Whh_b : Whh_f;
    f16x8 bfr[4][4];                     // [gate q][kk]
    #pragma unroll
    for (int q = 0; q < 4; ++q) {
        #pragma unroll
        for (int kk = 0; kk < 4; ++kk) {
            int n  = q * 128 + w * 16 + l15;
            int k0 = kk * 32 + l4 * 8;
            const float* src = Whh + (size_t)n * kH + k0;
            float4 x0 = *(const float4*)(src);
            float4 x1 = *(const float4*)(src + 4);
            f16x8 v;
            v[0] = (_Float16)x0.x; v[1] = (_Float16)x0.y;
            v[2] = (_Float16)x0.z; v[3] = (_Float16)x0.w;
            v[4] = (_Float16)x1.x; v[5] = (_Float16)x1.y;
            v[6] = (_Float16)x1.z; v[7] = (_Float16)x1.w;
            bfr[q][kk] = v;
        }
    }
    // ---- feats (Wt) B-fragments + bias on wave 0 ----
    f16x8 wtfr[4];
    float btv = 0.f;
    if (w == 0) {
        #pragma unroll
        for (int kk = 0; kk < 4; ++kk) {
            f16x8 v;
            #pragma unroll
            for (int j = 0; j < 8; ++j) {
                int kx = kk * 32 + l4 * 8 + j;
                float x = (l15 < kK) ? Wt[l15 * 256 + dir * kH + kx] : 0.f;
                v[j] = (_Float16)x;
            }
            wtfr[kk] = v;
        }
        btv = (l15 < kK && dir == 0) ? bt[l15] : 0.f;
    }

    // ---- per-lane chain rows and lengths ----
    int lenr[4];
    #pragma unroll
    for (int reg = 0; reg < 4; ++reg)
        lenr[reg] = lengths[g * kNB + l4 * 4 + reg];
    const int smax = lengths[g * kNB];   // sorted desc -> group max

    const int u = w * 16 + l15;          // this lane's unit column
    float cst[4] = {0.f, 0.f, 0.f, 0.f};
    float hst[4] = {0.f, 0.f, 0.f, 0.f};
    f16x8 afr[4];
    #pragma unroll
    for (int kk = 0; kk < 4; ++kk)
        #pragma unroll
        for (int j = 0; j < 8; ++j) afr[kk][j] = (_Float16)0.f;

    const _Float16* gip = gi + ((size_t)(dir * 8 + g) * kT) * 8192
                             + (size_t)(w * 64 + l) * 16;
    float* fout = dir ? feats_b : feats_f;

    int tfirst = dir ? (smax - 1) : 0;
    f16x8 gc0 = *(const f16x8*)(gip + (size_t)tfirst * 8192);
    f16x8 gc1 = *(const f16x8*)(gip + (size_t)tfirst * 8192 + 8);

    for (int s = 0; s < smax; ++s) {
        const int t = dir ? (smax - 1 - s) : s;
        // acc init from gi fragment (q*4+reg)
        f32x4 acc[4];
        #pragma unroll
        for (int reg = 0; reg < 4; ++reg) {
            acc[0][reg] = (float)gc0[reg];
            acc[1][reg] = (float)gc0[4 + reg];
            acc[2][reg] = (float)gc1[reg];
            acc[3][reg] = (float)gc1[4 + reg];
        }
        // prefetch next step's gi
        {
            int tn = dir ? (t > 0 ? t - 1 : 0) : (t + 1 < smax ? t + 1 : t);
            gc0 = *(const f16x8*)(gip + (size_t)tn * 8192);
            gc1 = *(const f16x8*)(gip + (size_t)tn * 8192 + 8);
        }
        // GEMM: g = gi + h @ Whh^T
        #pragma unroll
        for (int kk = 0; kk < 4; ++kk)
            #pragma unroll
            for (int q = 0; q < 4; ++q)
                acc[q] = __builtin_amdgcn_mfma_f32_16x16x32_f16(
                    afr[kk], bfr[q][kk], acc[q], 0, 0, 0);
        // activation (4 units per lane) + masked state update + h write
        #pragma unroll
        for (int reg = 0; reg < 4; ++reg) {
            float gi_ = acc[0][reg], gf_ = acc[1][reg];
            float gg_ = acc[2][reg], go_ = acc[3][reg];
            float cn = sigm(gf_) * cst[reg] + sigm(gi_) * tanh_(gg_);
            float hn = sigm(go_) * tanh_(cn);
            if (t < lenr[reg]) { cst[reg] = cn; hst[reg] = hn; }
            int r = l4 * 4 + reg;
            unsigned bo = ((unsigned)(r * 256 + u * 2)) ^ (unsigned)((r & 7) << 4);
            *(_Float16*)((char*)hbuf[s & 1] + bo) = (_Float16)hst[reg];
        }
        __syncthreads();
        // read h as next step's A-fragments (rows=chains, k=units)
        {
            const unsigned sw2 = (unsigned)((l15 & 7) << 4);
            #pragma unroll
            for (int kk = 0; kk < 4; ++kk) {
                unsigned bo = ((unsigned)(l15 * 256 + kk * 64 + l4 * 16)) ^ sw2;
                afr[kk] = *(const f16x8*)((const char*)hbuf[s & 1] + bo);
            }
        }
        // fused feats projection for step t on wave 0
        if (w == 0) {
            f32x4 f = {0.f, 0.f, 0.f, 0.f};
            #pragma unroll
            for (int kk = 0; kk < 4; ++kk)
                f = __builtin_amdgcn_mfma_f32_16x16x32_f16(
                    afr[kk], wtfr[kk], f, 0, 0, 0);
            if (l15 < kK) {
                #pragma unroll
                for (int reg = 0; reg < 4; ++reg) {
                    int b = g * kNB + l4 * 4 + reg;
                    fout[((size_t)b * kT + t) * kK + l15] = f[reg] + btv;
                }
            }
        }
    }
}

// ---------------------------------------------------------------------------
// Kernel 3: CRF Viterbi via max-plus matrix reduction tree. (unchanged)
// ---------------------------------------------------------------------------
__global__ __launch_bounds__(512) void viterbi_kernel(
    const int* __restrict__ lengths, const float* __restrict__ trans,
    const float* __restrict__ feats_f, const float* __restrict__ feats_b,
    float* __restrict__ out)
{
    constexpr float NEG = -1e30f;
    constexpr int RA = 0;            // region A: 128 matrices
    constexpr int RB = 128 * 81;     // region B: 64 matrices
    const int b = blockIdx.x;
    const int len = lengths[b];
    const int tid = threadIdx.x;

    __shared__ float tree[(128 + 64) * 81];
    __shared__ float fsum[kT * kK];
    __shared__ float trs[81];
    __shared__ float red[16];

    if (tid < 81) trs[tid] = trans[tid];
    for (int idx = tid; idx < len * kK; idx += 512)
        fsum[idx] = feats_f[(size_t)b * kT * kK + idx] +
                    feats_b[(size_t)b * kT * kK + idx];
    __syncthreads();

    // ---- fused level 0: each task = column j of R_s = M_{4s+3}..M_{4s} ----
    for (int task = tid; task < 128 * 9; task += 512) {
        int s = task / 9, j = task - s * 9;
        int tb = 4 * s;
        float uu[9];
        #pragma unroll
        for (int m = 0; m < 9; ++m)
            uu[m] = (tb < len) ? (trs[m * 9 + j] + fsum[tb * 9 + m])
                               : ((m == j) ? 0.f : NEG);
        #pragma unroll
        for (int q = 1; q < 4; ++q) {
            int t = tb + q;
            if (t < len) {
                float un[9];
                #pragma unroll
                for (int k = 0; k < 9; ++k) {
                    float v = trs[k * 9] + uu[0];
                    #pragma unroll
                    for (int m = 1; m < 9; ++m)
                        v = fmaxf(v, trs[k * 9 + m] + uu[m]);
                    un[k] = v + fsum[t * 9 + k];
                }
                #pragma unroll
                for (int k = 0; k < 9; ++k) uu[k] = un[k];
            }
        }
        #pragma unroll
        for (int k = 0; k < 9; ++k)
            tree[RA + s * 81 + k * 9 + j] = uu[k];
    }
    __syncthreads();

    // ---- tree levels: 64,32,...,1 matrices out ----
    int soff = RA, doff = RB;
    for (int np = 64; np >= 1; np >>= 1) {
        for (int idx = tid; idx < np * 81; idx += 512) {
            int s = idx / 81, o = idx - s * 81;
            int k = o / 9, j = o - k * 9;
            const float* A  = tree + soff + (2 * s + 1) * 81;
            const float* Bm = tree + soff + (2 * s) * 81;
            float v = A[k * 9] + Bm[j];
            #pragma unroll
            for (int m = 1; m < 9; ++m)
                v = fmaxf(v, A[k * 9 + m] + Bm[m * 9 + j]);
            tree[doff + s * 81 + o] = v;
        }
        int tmp = soff; soff = doff; doff = tmp;
        __syncthreads();
    }
    if (tid < kK) {
        int k = tid;
        float fv = tree[soff + k * 9 + kSTART];      // + fv0[START] = 0
        #pragma unroll
        for (int j = 0; j < 9; ++j)
            if (j != kSTART) fv = fmaxf(fv, tree[soff + k * 9 + j] - 10000.f);
        red[k] = fv + trs[kSTOP * 9 + k];
    }
    __syncthreads();
    if (tid == 0) {
        float m = red[0];
        #pragma unroll
        for (int k = 1; k < 9; ++k) m = fmaxf(m, red[k]);
        out[b] = m;
    }
}

// ---------------------------------------------------------------------------
extern "C" void kernel_launch(void* const* d_in, const int* in_sizes, int n_in,
                              void* d_out, int out_size, void* d_ws, size_t ws_size,
                              hipStream_t stream) {
    const int*   sentence = (const int*)d_in[0];
    const int*   lengths  = (const int*)d_in[1];
    const float* emb      = (const float*)d_in[2];
    const float* Wih_f    = (const float*)d_in[3];
    const float* Whh_f    = (const float*)d_in[4];
    const float* b_f      = (const float*)d_in[5];
    const float* Wih_b    = (const float*)d_in[6];
    const float* Whh_b    = (const float*)d_in[7];
    const float* b_b      = (const float*)d_in[8];
    const float* Wt       = (const float*)d_in[9];
    const float* bt       = (const float*)d_in[10];
    const float* trans    = (const float*)d_in[11];
    float* out = (float*)d_out;

    char* ws = (char*)d_ws;
    const size_t gi_bytes = (size_t)2 * kB * kT * kG * sizeof(_Float16); // 128 MiB
    const size_t ft_bytes = (size_t)kB * kT * kK * sizeof(float);        // 2.25 MiB
    _Float16* gi      = (_Float16*)ws;
    float*    feats_f = (float*)(ws + gi_bytes);
    float*    feats_b = (float*)(ws + gi_bytes + ft_bytes);

    dim3 g1((kB * kT) / 128, 1024 / 128);
    proj_kernel<<<g1, 256, 0, stream>>>(sentence, lengths, emb,
                                        Wih_f, b_f, Wih_b, b_b, gi);
    lstm_kernel<<<16, 512, 0, stream>>>(gi, lengths, Whh_f, Whh_b,
                                        Wt, bt, feats_f, feats_b);
    viterbi_kernel<<<128, 512, 0, stream>>>(lengths, trans, feats_f, feats_b, out);
}